// Round 1
// baseline (10025.891 us; speedup 1.0000x reference)
//
#include <hip/hip_runtime.h>
#include <hip/hip_bf16.h>

// LSTM T=1024 B=32 I=H=512.
// Phase 1 (per 256-step chunk): gx = x@Wx^T  (bf16 MFMA, 128x128 tile, fp32 out)
// Phase 2: persistent 64-block recurrence; Wh held in registers as MFMA B-frags;
//          h exchanged via double-buffered bf16 global buffer + flag barrier.

typedef __attribute__((ext_vector_type(8))) short short8;
typedef __attribute__((ext_vector_type(4))) float f32x4;

#define T_TOT 1024
#define T_CHUNK 256
#define BB 32
#define HH 512
#define G4 2048
#define NBLK 64
#define FLAG_STRIDE 32  // u32 per flag slot (128B line)

__device__ __forceinline__ unsigned short f2bf(float x) {
  union { float f; unsigned u; } v; v.f = x;
  unsigned r = v.u + 0x7FFFu + ((v.u >> 16) & 1u);
  return (unsigned short)(r >> 16);
}

// ---------------- f32 -> bf16 convert, 8 elems/thread ----------------
__global__ void cvt_bf16_kernel(const float* __restrict__ src,
                                unsigned short* __restrict__ dst, int n8) {
  int i = blockIdx.x * blockDim.x + threadIdx.x;
  if (i >= n8) return;
  const float4* s4 = (const float4*)src;
  float4 a = s4[2 * i], b = s4[2 * i + 1];
  short8 o;
  o[0] = (short)f2bf(a.x); o[1] = (short)f2bf(a.y);
  o[2] = (short)f2bf(a.z); o[3] = (short)f2bf(a.w);
  o[4] = (short)f2bf(b.x); o[5] = (short)f2bf(b.y);
  o[6] = (short)f2bf(b.z); o[7] = (short)f2bf(b.w);
  *(short8*)(dst + 8 * i) = o;
}

// ---------------- Phase 1: C[8192][2048] = A[8192][512] @ Bw[2048][512]^T ----------------
// grid (16 n-tiles, 64 m-tiles), 256 threads = 4 waves (2x2), each wave 64x64 out.
__global__ __launch_bounds__(256) void gemm_gx(
    const unsigned short* __restrict__ A,   // xb chunk [8192][512] bf16
    const unsigned short* __restrict__ Bw,  // Wxb [2048][512] bf16
    float* __restrict__ C)                  // gx chunk [8192][2048] f32
{
  __shared__ short As[128 * 64];
  __shared__ short Bs[128 * 64];
  const int tid = threadIdx.x;
  const int lane = tid & 63, wave = tid >> 6;
  const int wm = wave >> 1, wn = wave & 1;
  const int m0 = blockIdx.y * 128, n0 = blockIdx.x * 128;
  const int r = lane & 15, kg = lane >> 4;

  const f32x4 vzero = {0.f, 0.f, 0.f, 0.f};
  f32x4 acc[4][4];
#pragma unroll
  for (int i = 0; i < 4; ++i)
#pragma unroll
    for (int j = 0; j < 4; ++j) acc[i][j] = vzero;

  for (int kt = 0; kt < 8; ++kt) {
    const int k0 = kt * 64;
#pragma unroll
    for (int j = 0; j < 4; ++j) {
      int e = j * 2048 + tid * 8;  // element in 128x64 tile
      int row = e >> 6, col = e & 63;
      *(short8*)(As + e) = *(const short8*)(A + (m0 + row) * 512 + k0 + col);
      *(short8*)(Bs + e) = *(const short8*)(Bw + (n0 + row) * 512 + k0 + col);
    }
    __syncthreads();
#pragma unroll
    for (int ks = 0; ks < 2; ++ks) {
      short8 af[4], bfr[4];
#pragma unroll
      for (int mi = 0; mi < 4; ++mi)
        af[mi] = *(const short8*)(As + (wm * 64 + mi * 16 + r) * 64 + ks * 32 + kg * 8);
#pragma unroll
      for (int ni = 0; ni < 4; ++ni)
        bfr[ni] = *(const short8*)(Bs + (wn * 64 + ni * 16 + r) * 64 + ks * 32 + kg * 8);
#pragma unroll
      for (int mi = 0; mi < 4; ++mi)
#pragma unroll
        for (int ni = 0; ni < 4; ++ni)
          acc[mi][ni] = __builtin_amdgcn_mfma_f32_16x16x32_bf16(af[mi], bfr[ni], acc[mi][ni], 0, 0, 0);
    }
    __syncthreads();
  }
  // epilogue: D layout col=lane&15, row=(lane>>4)*4+j
  const int cc = lane & 15, rr4 = (lane >> 4) * 4;
#pragma unroll
  for (int mi = 0; mi < 4; ++mi) {
#pragma unroll
    for (int ni = 0; ni < 4; ++ni) {
      int gm = m0 + wm * 64 + mi * 16 + rr4;
      int gn = n0 + wn * 64 + ni * 16 + cc;
#pragma unroll
      for (int j = 0; j < 4; ++j) C[(gm + j) * 2048 + gn] = acc[mi][ni][j];
    }
  }
}

// ---------------- Phase 2: persistent recurrence ----------------
// 64 blocks x 256 thr. Block g owns units [g*8, g*8+8) (32 gate cols: i,f,g,o x 8).
// Wave (mt,nt): mt = batch half, nt = 16-col half. Wh B-frags live in registers.
__global__ __launch_bounds__(256) void lstm_seq(
    const float* __restrict__ gx,            // chunk [T_CHUNK][32][2048]
    const unsigned short* __restrict__ Whb,  // [2048][512] bf16
    const float* __restrict__ bias,          // [2048]
    const float* __restrict__ c0,            // [32][512]
    unsigned short* __restrict__ hb,         // [2][32][512] bf16
    float* __restrict__ cbuf,                // [32][512]
    unsigned int* __restrict__ flags,        // [64*FLAG_STRIDE]
    float* __restrict__ out,                 // full d_out
    int t0)
{
  const int g = blockIdx.x;
  const int tid = threadIdx.x;
  const int lane = tid & 63, wave = tid >> 6;
  const int mt = wave >> 1, nt = wave & 1;
  const int r = lane & 15, kg = lane >> 4;

  // B fragments (Wh rows) for this wave's 16 cols, resident all steps
  const int n_loc = nt * 16 + r;                       // 0..31
  const int urow = (n_loc >> 3) * 512 + g * 8 + (n_loc & 7);  // Wh row (gate-major)
  short8 bfrag[16];
#pragma unroll
  for (int s = 0; s < 16; ++s)
    bfrag[s] = *(const short8*)((const short*)Whb + urow * 512 + s * 32 + kg * 8);

  // cell-update mapping: thread -> (batch, local unit)
  const int ub = tid >> 3, uu = tid & 7;
  const int unit = g * 8 + uu;
  const float bi = bias[0 * 512 + unit], bff = bias[1 * 512 + unit],
              bg = bias[2 * 512 + unit], bo = bias[3 * 512 + unit];
  float cst = (t0 == 0) ? c0[ub * 512 + unit] : cbuf[ub * 512 + unit];

  __shared__ float gbuf[32][32];

  const long long hTO = (long long)T_TOT * BB * HH;
  const long long cTO = hTO + BB * HH;
  const long long ahO = cTO + BB * HH;

  for (int tt = 0; tt < T_CHUNK; ++tt) {
    const int t = t0 + tt;
    // prefetch gx for this step (latency hides under the poll)
    const float* gxp = gx + (long long)tt * BB * G4 + ub * G4;
    float xi = gxp[0 * 512 + unit], xf = gxp[1 * 512 + unit],
          xg = gxp[2 * 512 + unit], xo = gxp[3 * 512 + unit];

    if (t > 0) {
      if (wave == 0) {
        unsigned v; unsigned guard = 0;
        do {
          v = __hip_atomic_load(&flags[lane * FLAG_STRIDE], __ATOMIC_RELAXED,
                                __HIP_MEMORY_SCOPE_AGENT);
        } while (v < (unsigned)t && ++guard < (1u << 14));
      }
      __syncthreads();
      __builtin_amdgcn_fence(__ATOMIC_ACQUIRE, "agent");
    }

    // A = h_t [32][512] bf16; frag rows = batches
    const unsigned short* hcur = hb + (t & 1) * (BB * HH);
    short8 af[16];
#pragma unroll
    for (int s = 0; s < 16; ++s)
      af[s] = *(const short8*)((const short*)hcur + (mt * 16 + r) * 512 + s * 32 + kg * 8);
    f32x4 a0 = {0.f, 0.f, 0.f, 0.f}, a1 = {0.f, 0.f, 0.f, 0.f};
#pragma unroll
    for (int s = 0; s < 16; s += 2) {
      a0 = __builtin_amdgcn_mfma_f32_16x16x32_bf16(af[s], bfrag[s], a0, 0, 0, 0);
      a1 = __builtin_amdgcn_mfma_f32_16x16x32_bf16(af[s + 1], bfrag[s + 1], a1, 0, 0, 0);
    }
    f32x4 accv = a0 + a1;
    {
      const int rr4 = kg * 4;
#pragma unroll
      for (int j = 0; j < 4; ++j)
        gbuf[mt * 16 + rr4 + j][nt * 16 + r] = accv[j];
    }
    __syncthreads();

    // cell update (fp32)
    float gi = gbuf[ub][0 + uu] + xi + bi;
    float gf = gbuf[ub][8 + uu] + xf + bff;
    float gg = gbuf[ub][16 + uu] + xg + bg;
    float go = gbuf[ub][24 + uu] + xo + bo;
    float si = 1.f / (1.f + __expf(-gi));
    float sf = 1.f / (1.f + __expf(-gf));
    float so = 1.f / (1.f + __expf(-go));
    float tg = 2.f / (1.f + __expf(-2.f * gg)) - 1.f;
    cst = sf * cst + si * tg;
    float tc = 2.f / (1.f + __expf(-2.f * cst)) - 1.f;
    float hn = so * tc;

    long long oidx = (long long)t * BB * HH + ub * HH + unit;
    out[oidx] = hn;            // output
    out[ahO + oidx] = hn;      // all_hidden_state
    if (t == T_TOT - 1) {
      out[hTO + ub * HH + unit] = hn;
      out[cTO + ub * HH + unit] = cst;
    }
    hb[((t + 1) & 1) * (BB * HH) + ub * HH + unit] = f2bf(hn);
    if (tt == T_CHUNK - 1) cbuf[ub * 512 + unit] = cst;

    __builtin_amdgcn_fence(__ATOMIC_RELEASE, "agent");
    __syncthreads();
    if (tid == 0)
      __hip_atomic_store(&flags[g * FLAG_STRIDE], (unsigned)(t + 1),
                         __ATOMIC_RELAXED, __HIP_MEMORY_SCOPE_AGENT);
  }
}

extern "C" void kernel_launch(void* const* d_in, const int* in_sizes, int n_in,
                              void* d_out, int out_size, void* d_ws, size_t ws_size,
                              hipStream_t stream) {
  const float* x  = (const float*)d_in[0];   // [1024][32][512]
  const float* h0 = (const float*)d_in[1];   // [1][32][512]
  const float* c0 = (const float*)d_in[2];   // [1][32][512]
  const float* Wx = (const float*)d_in[3];   // [2048][512]
  const float* Wh = (const float*)d_in[4];   // [2048][512]
  const float* b  = (const float*)d_in[5];   // [2048]
  float* out = (float*)d_out;
  char* ws = (char*)d_ws;

  // ws layout (~100.1 MB total)
  float* gx            = (float*)ws;                            // 256*32*2048 f32 = 64 MB
  unsigned short* xb   = (unsigned short*)(ws + 67108864);      // 16.78M bf16 = 32 MB
  unsigned short* Wxb  = (unsigned short*)(ws + 100663296);     // 2 MB
  unsigned short* Whb  = (unsigned short*)(ws + 102760448);     // 2 MB
  unsigned short* hb   = (unsigned short*)(ws + 104857600);     // 64 KB
  float* cbuf          = (float*)(ws + 104923136);              // 64 KB
  unsigned int* flags  = (unsigned int*)(ws + 104988672);       // 8 KB

  hipMemsetAsync(flags, 0, NBLK * FLAG_STRIDE * 4, stream);

  // converts: x, Wx, Wh -> bf16; h0 -> hb[0]
  cvt_bf16_kernel<<<8192, 256, 0, stream>>>(x, xb, 16777216 / 8);
  cvt_bf16_kernel<<<512, 256, 0, stream>>>(Wx, Wxb, 1048576 / 8);
  cvt_bf16_kernel<<<512, 256, 0, stream>>>(Wh, Whb, 1048576 / 8);
  cvt_bf16_kernel<<<8, 256, 0, stream>>>(h0, hb, 16384 / 8);

  for (int ch = 0; ch < 4; ++ch) {
    gemm_gx<<<dim3(16, 64), 256, 0, stream>>>(xb + (size_t)ch * 8192 * 512, Wxb, gx);
    lstm_seq<<<NBLK, 256, 0, stream>>>(gx, Whb, b, c0, hb, cbuf, flags, out,
                                       ch * T_CHUNK);
  }
}

// Round 2
// 5660.727 us; speedup vs baseline: 1.7711x; 1.7711x over previous
//
#include <hip/hip_runtime.h>
#include <hip/hip_bf16.h>

// LSTM T=1024 B=32 I=H=512.
// Phase 1 (per 256-step chunk): gx = x@Wx^T  (bf16 MFMA, 128x128 tile, fp32 out)
// Phase 2: persistent 64-block recurrence; Wh held in registers as MFMA B-frags;
//          h exchanged via LLC-coherent (agent-scope sc1) atomics + per-block flags.
//          NO acquire/release fences (they buffer_inv/wbl2 the L2 every step).

typedef __attribute__((ext_vector_type(8))) short short8;
typedef __attribute__((ext_vector_type(4))) float f32x4;

#define T_TOT 1024
#define T_CHUNK 256
#define BB 32
#define HH 512
#define G4 2048
#define NBLK 64
#define FLAG_STRIDE 32  // u32 per flag slot (128B line)

__device__ __forceinline__ unsigned short f2bf(float x) {
  union { float f; unsigned u; } v; v.f = x;
  unsigned r = v.u + 0x7FFFu + ((v.u >> 16) & 1u);
  return (unsigned short)(r >> 16);
}

// ---------------- f32 -> bf16 convert, 8 elems/thread ----------------
__global__ void cvt_bf16_kernel(const float* __restrict__ src,
                                unsigned short* __restrict__ dst, int n8) {
  int i = blockIdx.x * blockDim.x + threadIdx.x;
  if (i >= n8) return;
  const float4* s4 = (const float4*)src;
  float4 a = s4[2 * i], b = s4[2 * i + 1];
  short8 o;
  o[0] = (short)f2bf(a.x); o[1] = (short)f2bf(a.y);
  o[2] = (short)f2bf(a.z); o[3] = (short)f2bf(a.w);
  o[4] = (short)f2bf(b.x); o[5] = (short)f2bf(b.y);
  o[6] = (short)f2bf(b.z); o[7] = (short)f2bf(b.w);
  *(short8*)(dst + 8 * i) = o;
}

// ---------------- Phase 1: C[8192][2048] = A[8192][512] @ Bw[2048][512]^T ----------------
__global__ __launch_bounds__(256) void gemm_gx(
    const unsigned short* __restrict__ A,   // xb chunk [8192][512] bf16
    const unsigned short* __restrict__ Bw,  // Wxb [2048][512] bf16
    float* __restrict__ C)                  // gx chunk [8192][2048] f32
{
  __shared__ short As[128 * 64];
  __shared__ short Bs[128 * 64];
  const int tid = threadIdx.x;
  const int lane = tid & 63, wave = tid >> 6;
  const int wm = wave >> 1, wn = wave & 1;
  const int m0 = blockIdx.y * 128, n0 = blockIdx.x * 128;
  const int r = lane & 15, kg = lane >> 4;

  const f32x4 vzero = {0.f, 0.f, 0.f, 0.f};
  f32x4 acc[4][4];
#pragma unroll
  for (int i = 0; i < 4; ++i)
#pragma unroll
    for (int j = 0; j < 4; ++j) acc[i][j] = vzero;

  for (int kt = 0; kt < 8; ++kt) {
    const int k0 = kt * 64;
#pragma unroll
    for (int j = 0; j < 4; ++j) {
      int e = j * 2048 + tid * 8;  // element in 128x64 tile
      int row = e >> 6, col = e & 63;
      *(short8*)(As + e) = *(const short8*)(A + (m0 + row) * 512 + k0 + col);
      *(short8*)(Bs + e) = *(const short8*)(Bw + (n0 + row) * 512 + k0 + col);
    }
    __syncthreads();
#pragma unroll
    for (int ks = 0; ks < 2; ++ks) {
      short8 af[4], bfr[4];
#pragma unroll
      for (int mi = 0; mi < 4; ++mi)
        af[mi] = *(const short8*)(As + (wm * 64 + mi * 16 + r) * 64 + ks * 32 + kg * 8);
#pragma unroll
      for (int ni = 0; ni < 4; ++ni)
        bfr[ni] = *(const short8*)(Bs + (wn * 64 + ni * 16 + r) * 64 + ks * 32 + kg * 8);
#pragma unroll
      for (int mi = 0; mi < 4; ++mi)
#pragma unroll
        for (int ni = 0; ni < 4; ++ni)
          acc[mi][ni] = __builtin_amdgcn_mfma_f32_16x16x32_bf16(af[mi], bfr[ni], acc[mi][ni], 0, 0, 0);
    }
    __syncthreads();
  }
  const int cc = lane & 15, rr4 = (lane >> 4) * 4;
#pragma unroll
  for (int mi = 0; mi < 4; ++mi) {
#pragma unroll
    for (int ni = 0; ni < 4; ++ni) {
      int gm = m0 + wm * 64 + mi * 16 + rr4;
      int gn = n0 + wn * 64 + ni * 16 + cc;
#pragma unroll
      for (int j = 0; j < 4; ++j) C[(gm + j) * 2048 + gn] = acc[mi][ni][j];
    }
  }
}

// ---------------- Phase 2: persistent recurrence ----------------
// 64 blocks x 256 thr, 1 block/CU (launch_bounds min-waves=1 -> full VGPR budget,
// Wh B-frags stay register-resident). Block g owns units [g*8, g*8+8).
__global__ __launch_bounds__(256, 1) void lstm_seq(
    const float* __restrict__ gx,            // chunk [T_CHUNK][32][2048]
    const unsigned short* __restrict__ Whb,  // [2048][512] bf16
    const float* __restrict__ bias,          // [2048]
    const float* __restrict__ c0,            // [32][512]
    unsigned short* __restrict__ hb,         // [2][32][512] bf16
    float* __restrict__ cbuf,                // [32][512]
    unsigned int* __restrict__ flags,        // [64*FLAG_STRIDE]
    float* __restrict__ out,                 // full d_out
    int t0)
{
  const int g = blockIdx.x;
  const int tid = threadIdx.x;
  const int lane = tid & 63, wave = tid >> 6;
  const int mt = wave >> 1, nt = wave & 1;
  const int r = lane & 15, kg = lane >> 4;

  // B fragments (Wh rows) for this wave's 16 cols, resident all steps
  const int n_loc = nt * 16 + r;                              // 0..31
  const int urow = (n_loc >> 3) * 512 + g * 8 + (n_loc & 7);  // Wh row (gate-major)
  short8 bfrag[16];
#pragma unroll
  for (int s = 0; s < 16; ++s)
    bfrag[s] = *(const short8*)((const short*)Whb + urow * 512 + s * 32 + kg * 8);

  // cell-update mapping: thread -> (batch, local unit)
  const int ub = tid >> 3, uu = tid & 7;
  const int unit = g * 8 + uu;
  const float bi = bias[0 * 512 + unit], bff = bias[1 * 512 + unit],
              bg = bias[2 * 512 + unit], bo = bias[3 * 512 + unit];
  float cst = (t0 == 0) ? c0[ub * 512 + unit] : cbuf[ub * 512 + unit];

  __shared__ float gbuf[32][32];

  const long long hTO = (long long)T_TOT * BB * HH;
  const long long cTO = hTO + BB * HH;
  const long long ahO = cTO + BB * HH;

  for (int tt = 0; tt < T_CHUNK; ++tt) {
    const int t = t0 + tt;
    // prefetch gx for this step (plain cached loads; latency hides under poll)
    const float* gxp = gx + (long long)tt * BB * G4 + ub * G4;
    float xi = gxp[0 * 512 + unit], xf = gxp[1 * 512 + unit],
          xg = gxp[2 * 512 + unit], xo = gxp[3 * 512 + unit];

    // every wave polls all 64 flags (lane l -> flag l); passes trivially at t==0
    {
      unsigned v, guard = 0;
      do {
        v = __hip_atomic_load(&flags[lane * FLAG_STRIDE], __ATOMIC_RELAXED,
                              __HIP_MEMORY_SCOPE_AGENT);
      } while (v < (unsigned)t && ++guard < (1u << 14));
    }

    // A = h_t [32][512] bf16, read LLC-coherent (sc1) as u64 atomics
    const unsigned long long* hq =
        (const unsigned long long*)(hb + (t & 1) * (BB * HH));
    short8 af[16];
#pragma unroll
    for (int s = 0; s < 16; ++s) {
      int base = ((mt * 16 + r) * 512 + s * 32 + kg * 8) >> 2;  // u64 index
      union { unsigned long long q[2]; short8 v; } u;
      u.q[0] = __hip_atomic_load(&hq[base], __ATOMIC_RELAXED,
                                 __HIP_MEMORY_SCOPE_AGENT);
      u.q[1] = __hip_atomic_load(&hq[base + 1], __ATOMIC_RELAXED,
                                 __HIP_MEMORY_SCOPE_AGENT);
      af[s] = u.v;
    }
    f32x4 a0 = {0.f, 0.f, 0.f, 0.f}, a1 = {0.f, 0.f, 0.f, 0.f};
#pragma unroll
    for (int s = 0; s < 16; s += 2) {
      a0 = __builtin_amdgcn_mfma_f32_16x16x32_bf16(af[s], bfrag[s], a0, 0, 0, 0);
      a1 = __builtin_amdgcn_mfma_f32_16x16x32_bf16(af[s + 1], bfrag[s + 1], a1, 0, 0, 0);
    }
    f32x4 accv = a0 + a1;
    {
      const int rr4 = kg * 4;
#pragma unroll
      for (int j = 0; j < 4; ++j)
        gbuf[mt * 16 + rr4 + j][nt * 16 + r] = accv[j];
    }
    __syncthreads();

    // cell update (fp32)
    float gi = gbuf[ub][0 + uu] + xi + bi;
    float gf = gbuf[ub][8 + uu] + xf + bff;
    float gg = gbuf[ub][16 + uu] + xg + bg;
    float go = gbuf[ub][24 + uu] + xo + bo;
    float si = 1.f / (1.f + __expf(-gi));
    float sf = 1.f / (1.f + __expf(-gf));
    float so = 1.f / (1.f + __expf(-go));
    float tg = 2.f / (1.f + __expf(-2.f * gg)) - 1.f;
    cst = sf * cst + si * tg;
    float tc = 2.f / (1.f + __expf(-2.f * cst)) - 1.f;
    float hn = so * tc;

    // h_{t+1} store, LLC-coherent: pack 2 bf16 per u32 (even uu stores)
    unsigned short hbf = f2bf(hn);
    unsigned nb = (unsigned)__shfl_down((int)hbf, 1, 64);
    if (!(uu & 1)) {
      unsigned w = (unsigned)hbf | (nb << 16);
      unsigned* hw = (unsigned*)(hb + ((t + 1) & 1) * (BB * HH));
      __hip_atomic_store(&hw[(ub * 512 + unit) >> 1], w, __ATOMIC_RELAXED,
                         __HIP_MEMORY_SCOPE_AGENT);
    }
    // barrier drains each wave's vmcnt (h stores acked at LLC) before flag
    __syncthreads();
    if (tid == 0)
      __hip_atomic_store(&flags[g * FLAG_STRIDE], (unsigned)(t + 1),
                         __ATOMIC_RELAXED, __HIP_MEMORY_SCOPE_AGENT);

    // out stores after the flag: overlap next step's poll
    long long oidx = (long long)t * BB * HH + ub * HH + unit;
    out[oidx] = hn;            // output
    out[ahO + oidx] = hn;      // all_hidden_state
    if (t == T_TOT - 1) {
      out[hTO + ub * HH + unit] = hn;
      out[cTO + ub * HH + unit] = cst;
    }
    if (tt == T_CHUNK - 1) cbuf[ub * 512 + unit] = cst;
  }
}

extern "C" void kernel_launch(void* const* d_in, const int* in_sizes, int n_in,
                              void* d_out, int out_size, void* d_ws, size_t ws_size,
                              hipStream_t stream) {
  const float* x  = (const float*)d_in[0];   // [1024][32][512]
  const float* h0 = (const float*)d_in[1];   // [1][32][512]
  const float* c0 = (const float*)d_in[2];   // [1][32][512]
  const float* Wx = (const float*)d_in[3];   // [2048][512]
  const float* Wh = (const float*)d_in[4];   // [2048][512]
  const float* b  = (const float*)d_in[5];   // [2048]
  float* out = (float*)d_out;
  char* ws = (char*)d_ws;

  // ws layout (~100.1 MB total)
  float* gx            = (float*)ws;                            // 256*32*2048 f32 = 64 MB
  unsigned short* xb   = (unsigned short*)(ws + 67108864);      // 16.78M bf16 = 32 MB
  unsigned short* Wxb  = (unsigned short*)(ws + 100663296);     // 2 MB
  unsigned short* Whb  = (unsigned short*)(ws + 102760448);     // 2 MB
  unsigned short* hb   = (unsigned short*)(ws + 104857600);     // 64 KB
  float* cbuf          = (float*)(ws + 104923136);              // 64 KB
  unsigned int* flags  = (unsigned int*)(ws + 104988672);       // 8 KB

  hipMemsetAsync(flags, 0, NBLK * FLAG_STRIDE * 4, stream);

  // converts: x, Wx, Wh -> bf16; h0 -> hb[0]
  cvt_bf16_kernel<<<8192, 256, 0, stream>>>(x, xb, 16777216 / 8);
  cvt_bf16_kernel<<<512, 256, 0, stream>>>(Wx, Wxb, 1048576 / 8);
  cvt_bf16_kernel<<<512, 256, 0, stream>>>(Wh, Whb, 1048576 / 8);
  cvt_bf16_kernel<<<8, 256, 0, stream>>>(h0, hb, 16384 / 8);

  for (int ch = 0; ch < 4; ++ch) {
    gemm_gx<<<dim3(16, 64), 256, 0, stream>>>(xb + (size_t)ch * 8192 * 512, Wxb, gx);
    lstm_seq<<<NBLK, 256, 0, stream>>>(gx, Whb, b, c0, hb, cbuf, flags, out,
                                       ch * T_CHUNK);
  }
}

// Round 3
// 4396.553 us; speedup vs baseline: 2.2804x; 1.2875x over previous
//
#include <hip/hip_runtime.h>
#include <hip/hip_bf16.h>

// LSTM T=1024 B=32 I=H=512.
// Phase 1 (per 256-step chunk): gx = x@Wx^T  (bf16 MFMA, 128x128 tile, fp32 out)
// Phase 2: persistent 16-block x 512-thread recurrence.
//   - block g owns 32 units (128 gate-cols, cache-line aligned in gx/h)
//   - Wh B-frags pinned in VGPRs (asm anti-remat)
//   - h exchanged via LLC (agent-scope sc1) loads/stores; per-block flags;
//     wave w polls only flags {2w,2w+1} and stages those producers' columns.

typedef __attribute__((ext_vector_type(8))) short short8;
typedef __attribute__((ext_vector_type(4))) float f32x4;

#define T_TOT 1024
#define T_CHUNK 256
#define BB 32
#define HH 512
#define G4 2048
#define NBLK 16
#define FLAG_STRIDE 32  // u32 per flag slot (128B line)

__device__ __forceinline__ unsigned short f2bf(float x) {
  union { float f; unsigned u; } v; v.f = x;
  unsigned r = v.u + 0x7FFFu + ((v.u >> 16) & 1u);
  return (unsigned short)(r >> 16);
}

__device__ __forceinline__ f32x4 mfma16(short8 a, short8 b, f32x4 c) {
  return __builtin_amdgcn_mfma_f32_16x16x32_bf16(a, b, c, 0, 0, 0);
}

// ---------------- f32 -> bf16 convert, 8 elems/thread ----------------
__global__ void cvt_bf16_kernel(const float* __restrict__ src,
                                unsigned short* __restrict__ dst, int n8) {
  int i = blockIdx.x * blockDim.x + threadIdx.x;
  if (i >= n8) return;
  const float4* s4 = (const float4*)src;
  float4 a = s4[2 * i], b = s4[2 * i + 1];
  short8 o;
  o[0] = (short)f2bf(a.x); o[1] = (short)f2bf(a.y);
  o[2] = (short)f2bf(a.z); o[3] = (short)f2bf(a.w);
  o[4] = (short)f2bf(b.x); o[5] = (short)f2bf(b.y);
  o[6] = (short)f2bf(b.z); o[7] = (short)f2bf(b.w);
  *(short8*)(dst + 8 * i) = o;
}

// ---------------- Phase 1: C[8192][2048] = A[8192][512] @ Bw[2048][512]^T ----------------
__global__ __launch_bounds__(256) void gemm_gx(
    const unsigned short* __restrict__ A,
    const unsigned short* __restrict__ Bw,
    float* __restrict__ C)
{
  __shared__ short As[128 * 64];
  __shared__ short Bs[128 * 64];
  const int tid = threadIdx.x;
  const int lane = tid & 63, wave = tid >> 6;
  const int wm = wave >> 1, wn = wave & 1;
  const int m0 = blockIdx.y * 128, n0 = blockIdx.x * 128;
  const int r = lane & 15, kg = lane >> 4;

  const f32x4 vzero = {0.f, 0.f, 0.f, 0.f};
  f32x4 acc[4][4];
#pragma unroll
  for (int i = 0; i < 4; ++i)
#pragma unroll
    for (int j = 0; j < 4; ++j) acc[i][j] = vzero;

  for (int kt = 0; kt < 8; ++kt) {
    const int k0 = kt * 64;
#pragma unroll
    for (int j = 0; j < 4; ++j) {
      int e = j * 2048 + tid * 8;
      int row = e >> 6, col = e & 63;
      *(short8*)(As + e) = *(const short8*)(A + (m0 + row) * 512 + k0 + col);
      *(short8*)(Bs + e) = *(const short8*)(Bw + (n0 + row) * 512 + k0 + col);
    }
    __syncthreads();
#pragma unroll
    for (int ks = 0; ks < 2; ++ks) {
      short8 af[4], bfr[4];
#pragma unroll
      for (int mi = 0; mi < 4; ++mi)
        af[mi] = *(const short8*)(As + (wm * 64 + mi * 16 + r) * 64 + ks * 32 + kg * 8);
#pragma unroll
      for (int ni = 0; ni < 4; ++ni)
        bfr[ni] = *(const short8*)(Bs + (wn * 64 + ni * 16 + r) * 64 + ks * 32 + kg * 8);
#pragma unroll
      for (int mi = 0; mi < 4; ++mi)
#pragma unroll
        for (int ni = 0; ni < 4; ++ni)
          acc[mi][ni] = mfma16(af[mi], bfr[ni], acc[mi][ni]);
    }
    __syncthreads();
  }
  const int cc = lane & 15, rr4 = (lane >> 4) * 4;
#pragma unroll
  for (int mi = 0; mi < 4; ++mi) {
#pragma unroll
    for (int ni = 0; ni < 4; ++ni) {
      int gm = m0 + wm * 64 + mi * 16 + rr4;
      int gn = n0 + wn * 64 + ni * 16 + cc;
#pragma unroll
      for (int j = 0; j < 4; ++j) C[(gm + j) * 2048 + gn] = acc[mi][ni][j];
    }
  }
}

// ---------------- Phase 2: persistent recurrence ----------------
__global__ __launch_bounds__(512, 2) void lstm_seq(
    const float* __restrict__ gx,            // chunk [T_CHUNK][32][2048]
    const unsigned short* __restrict__ Whb,  // [2048][512] bf16
    const float* __restrict__ bias,          // [2048]
    const float* __restrict__ c0,            // [32][512]
    unsigned short* __restrict__ hb,         // [2][32][512] bf16
    float* __restrict__ cbuf,                // [32][512]
    unsigned int* __restrict__ flags,        // [16*FLAG_STRIDE]
    float* __restrict__ out,                 // full d_out
    int t0)
{
  const int g = blockIdx.x;
  const int tid = threadIdx.x;
  const int lane = tid & 63, wave = tid >> 6;
  const int mt = wave >> 2, nt = wave & 3;   // batch half, gate
  const int r = lane & 15, kg = lane >> 4;

  // B fragments: Wh rows for gate nt, units g*32 + ct*16 + r, 16 K-slices
  short8 bfrag[2][16];
#pragma unroll
  for (int ct = 0; ct < 2; ++ct) {
    const int urow = nt * HH + g * 32 + ct * 16 + r;
#pragma unroll
    for (int s = 0; s < 16; ++s)
      bfrag[ct][s] = *(const short8*)((const short*)Whb + urow * HH + s * 32 + kg * 8);
  }
  // pin: values become asm outputs -> not rematerializable from Whb
#pragma unroll
  for (int ct = 0; ct < 2; ++ct)
#pragma unroll
    for (int s = 0; s < 16; ++s)
      asm volatile("" : "+v"(bfrag[ct][s]));

  // cell mapping: thread -> (batch b, units u2, u2+1)
  const int b = tid >> 4, u2 = (tid & 15) * 2;
  const int unit0 = g * 32 + u2;
  const float bi0 = bias[0 * HH + unit0], bi1 = bias[0 * HH + unit0 + 1];
  const float bf0 = bias[1 * HH + unit0], bf1 = bias[1 * HH + unit0 + 1];
  const float bg0 = bias[2 * HH + unit0], bg1 = bias[2 * HH + unit0 + 1];
  const float bo0 = bias[3 * HH + unit0], bo1 = bias[3 * HH + unit0 + 1];
  float cst0, cst1;
  if (t0 == 0) { cst0 = c0[b * HH + unit0]; cst1 = c0[b * HH + unit0 + 1]; }
  else         { cst0 = cbuf[b * HH + unit0]; cst1 = cbuf[b * HH + unit0 + 1]; }

  __shared__ unsigned short hs[BB * HH];   // XOR-swizzled h tile (32 KB)
  __shared__ float gbuf[4][BB][32];        // gate pre-acts (16 KB)

  const long long hTO = (long long)T_TOT * BB * HH;
  const long long cTO = hTO + BB * HH;
  const long long ahO = cTO + BB * HH;

  for (int tt = 0; tt < T_CHUNK; ++tt) {
    const int t = t0 + tt;
    // gx prefetch (plain cached loads; line-exact for this block)
    const float* gxp = gx + (long long)tt * BB * G4 + b * G4 + unit0;
    const float2 xi = *(const float2*)(gxp + 0 * HH);
    const float2 xf = *(const float2*)(gxp + 1 * HH);
    const float2 xg = *(const float2*)(gxp + 2 * HH);
    const float2 xo = *(const float2*)(gxp + 3 * HH);

    // poll: lanes 0/1 of wave w watch flags 2w, 2w+1
    if (lane < 2) {
      const unsigned* fp = &flags[(2 * wave + lane) * FLAG_STRIDE];
      unsigned v, guard = 0;
      do {
        v = __hip_atomic_load(fp, __ATOMIC_RELAXED, __HIP_MEMORY_SCOPE_AGENT);
      } while (v < (unsigned)t && ++guard < (1u << 14));
    }

    // stage h cols [wave*64, wave*64+64) (producers 2w,2w+1) into swizzled LDS
    {
      const unsigned long long* hq =
          (const unsigned long long*)(hb + (t & 1) * (BB * HH));
#pragma unroll
      for (int i = 0; i < 8; ++i) {
        int idx = i * 64 + lane;              // 0..511
        int row = idx >> 4, c4 = idx & 15;
        unsigned long long q = __hip_atomic_load(
            &hq[row * 128 + wave * 16 + c4], __ATOMIC_RELAXED,
            __HIP_MEMORY_SCOPE_AGENT);
        int off = (row * 1024 + wave * 128 + c4 * 8) ^ ((row & 7) << 4);
        *(unsigned long long*)((char*)hs + off) = q;
      }
    }
    __syncthreads();   // B1: all flags verified + h staged

    // MFMA: gate nt, batches mt*16..+16, 2 col-tiles of 16
    f32x4 aE0 = {0, 0, 0, 0}, aO0 = {0, 0, 0, 0};
    f32x4 aE1 = {0, 0, 0, 0}, aO1 = {0, 0, 0, 0};
    const int abase = (mt * 16 + r) * 1024;
    const int aswz = (r & 7) << 4;
#pragma unroll
    for (int s = 0; s < 16; s += 2) {
      short8 a0 = *(const short8*)((const char*)hs + ((abase + s * 64 + kg * 16) ^ aswz));
      short8 a1 = *(const short8*)((const char*)hs + ((abase + (s + 1) * 64 + kg * 16) ^ aswz));
      aE0 = mfma16(a0, bfrag[0][s], aE0);
      aE1 = mfma16(a0, bfrag[1][s], aE1);
      aO0 = mfma16(a1, bfrag[0][s + 1], aO0);
      aO1 = mfma16(a1, bfrag[1][s + 1], aO1);
    }
    const f32x4 acc0 = aE0 + aO0, acc1 = aE1 + aO1;
#pragma unroll
    for (int j = 0; j < 4; ++j) {
      gbuf[nt][mt * 16 + kg * 4 + j][r] = acc0[j];
      gbuf[nt][mt * 16 + kg * 4 + j][16 + r] = acc1[j];
    }
    __syncthreads();   // B2

    // cell update: 2 cells
    float gi0 = gbuf[0][b][u2] + xi.x + bi0, gi1 = gbuf[0][b][u2 + 1] + xi.y + bi1;
    float gf0_ = gbuf[1][b][u2] + xf.x + bf0, gf1_ = gbuf[1][b][u2 + 1] + xf.y + bf1;
    float gg0 = gbuf[2][b][u2] + xg.x + bg0, gg1 = gbuf[2][b][u2 + 1] + xg.y + bg1;
    float go0 = gbuf[3][b][u2] + xo.x + bo0, go1 = gbuf[3][b][u2 + 1] + xo.y + bo1;
    float si0 = 1.f / (1.f + __expf(-gi0)), si1 = 1.f / (1.f + __expf(-gi1));
    float sf0 = 1.f / (1.f + __expf(-gf0_)), sf1 = 1.f / (1.f + __expf(-gf1_));
    float so0 = 1.f / (1.f + __expf(-go0)), so1 = 1.f / (1.f + __expf(-go1));
    float tg0 = 2.f / (1.f + __expf(-2.f * gg0)) - 1.f;
    float tg1 = 2.f / (1.f + __expf(-2.f * gg1)) - 1.f;
    cst0 = sf0 * cst0 + si0 * tg0;
    cst1 = sf1 * cst1 + si1 * tg1;
    float tc0 = 2.f / (1.f + __expf(-2.f * cst0)) - 1.f;
    float tc1 = 2.f / (1.f + __expf(-2.f * cst1)) - 1.f;
    float hn0 = so0 * tc0, hn1 = so1 * tc1;

    // h_{t+1} store (LLC-coherent), packed pair
    unsigned w32 = (unsigned)f2bf(hn0) | ((unsigned)f2bf(hn1) << 16);
    unsigned* hw = (unsigned*)(hb + ((t + 1) & 1) * (BB * HH));
    __hip_atomic_store(&hw[(b * HH + unit0) >> 1], w32, __ATOMIC_RELAXED,
                       __HIP_MEMORY_SCOPE_AGENT);
    __syncthreads();   // B3: drains vmcnt per wave -> h stores acked at LLC
    if (tid == 0)
      __hip_atomic_store(&flags[g * FLAG_STRIDE], (unsigned)(t + 1),
                         __ATOMIC_RELAXED, __HIP_MEMORY_SCOPE_AGENT);

    // outputs after the flag (overlap next step's poll)
    long long oidx = (long long)t * BB * HH + b * HH + unit0;
    float2 hv; hv.x = hn0; hv.y = hn1;
    *(float2*)&out[oidx] = hv;
    *(float2*)&out[ahO + oidx] = hv;
    if (t == T_TOT - 1) {
      *(float2*)&out[hTO + b * HH + unit0] = hv;
      float2 cv; cv.x = cst0; cv.y = cst1;
      *(float2*)&out[cTO + b * HH + unit0] = cv;
    }
    if (tt == T_CHUNK - 1) {
      cbuf[b * HH + unit0] = cst0;
      cbuf[b * HH + unit0 + 1] = cst1;
    }
  }
}

extern "C" void kernel_launch(void* const* d_in, const int* in_sizes, int n_in,
                              void* d_out, int out_size, void* d_ws, size_t ws_size,
                              hipStream_t stream) {
  const float* x  = (const float*)d_in[0];
  const float* h0 = (const float*)d_in[1];
  const float* c0 = (const float*)d_in[2];
  const float* Wx = (const float*)d_in[3];
  const float* Wh = (const float*)d_in[4];
  const float* b  = (const float*)d_in[5];
  float* out = (float*)d_out;
  char* ws = (char*)d_ws;

  float* gx            = (float*)ws;                            // 64 MB
  unsigned short* xb   = (unsigned short*)(ws + 67108864);      // 32 MB
  unsigned short* Wxb  = (unsigned short*)(ws + 100663296);     // 2 MB
  unsigned short* Whb  = (unsigned short*)(ws + 102760448);     // 2 MB
  unsigned short* hb   = (unsigned short*)(ws + 104857600);     // 64 KB
  float* cbuf          = (float*)(ws + 104923136);              // 64 KB
  unsigned int* flags  = (unsigned int*)(ws + 104988672);       // 2 KB

  hipMemsetAsync(flags, 0, NBLK * FLAG_STRIDE * 4, stream);

  cvt_bf16_kernel<<<8192, 256, 0, stream>>>(x, xb, 16777216 / 8);
  cvt_bf16_kernel<<<512, 256, 0, stream>>>(Wx, Wxb, 1048576 / 8);
  cvt_bf16_kernel<<<512, 256, 0, stream>>>(Wh, Whb, 1048576 / 8);
  cvt_bf16_kernel<<<8, 256, 0, stream>>>(h0, hb, 16384 / 8);

  for (int ch = 0; ch < 4; ++ch) {
    gemm_gx<<<dim3(16, 64), 256, 0, stream>>>(xb + (size_t)ch * 8192 * 512, Wxb, gx);
    lstm_seq<<<NBLK, 512, 0, stream>>>(gx, Whb, b, c0, hb, cbuf, flags, out,
                                       ch * T_CHUNK);
  }
}

// Round 4
// 3319.461 us; speedup vs baseline: 3.0203x; 1.3245x over previous
//
#include <hip/hip_runtime.h>
#include <hip/hip_bf16.h>

// LSTM T=1024 B=32 I=H=512.
// Phase 1 (per 128-step chunk): gx = x@Wx^T  (bf16 MFMA, 128x128 tile, fp32 out)
// Phase 2: persistent 16-block x 512-thread recurrence, FLAGLESS:
//   - hseq[t] is a per-timestep 32KB bf16 h slot, pre-filled with sentinel
//     0x7F80 (bf16 +inf; h=tanh*sigmoid can never be inf)
//   - producers sc1-store h pairs into slot t+1 (no drain, no flag, no barrier)
//   - consumers poll their own coalesced u64 loads of slot t until no half
//     equals the sentinel; the successful poll IS the data load
//   - Wh B-frags pinned in VGPRs (asm anti-remat)

typedef __attribute__((ext_vector_type(8))) short short8;
typedef __attribute__((ext_vector_type(4))) float f32x4;

#define T_TOT 1024
#define T_CHUNK 128
#define NCHUNK 8
#define BB 32
#define HH 512
#define G4 2048
#define NBLK 16
#define SENT32 0x7F807F80u

__device__ __forceinline__ unsigned short f2bf(float x) {
  union { float f; unsigned u; } v; v.f = x;
  unsigned r = v.u + 0x7FFFu + ((v.u >> 16) & 1u);
  return (unsigned short)(r >> 16);
}

__device__ __forceinline__ f32x4 mfma16(short8 a, short8 b, f32x4 c) {
  return __builtin_amdgcn_mfma_f32_16x16x32_bf16(a, b, c, 0, 0, 0);
}

// ---------------- sentinel fill (uint4 stores) ----------------
__global__ void fill_sentinel(uint4* __restrict__ p, int n16) {
  int i = blockIdx.x * blockDim.x + threadIdx.x;
  if (i >= n16) return;
  uint4 v; v.x = SENT32; v.y = SENT32; v.z = SENT32; v.w = SENT32;
  p[i] = v;
}

// ---------------- f32 -> bf16 convert, 8 elems/thread ----------------
__global__ void cvt_bf16_kernel(const float* __restrict__ src,
                                unsigned short* __restrict__ dst, int n8) {
  int i = blockIdx.x * blockDim.x + threadIdx.x;
  if (i >= n8) return;
  const float4* s4 = (const float4*)src;
  float4 a = s4[2 * i], b = s4[2 * i + 1];
  short8 o;
  o[0] = (short)f2bf(a.x); o[1] = (short)f2bf(a.y);
  o[2] = (short)f2bf(a.z); o[3] = (short)f2bf(a.w);
  o[4] = (short)f2bf(b.x); o[5] = (short)f2bf(b.y);
  o[6] = (short)f2bf(b.z); o[7] = (short)f2bf(b.w);
  *(short8*)(dst + 8 * i) = o;
}

// ---------------- Phase 1: C[4096][2048] = A[4096][512] @ Bw[2048][512]^T ----------------
__global__ __launch_bounds__(256) void gemm_gx(
    const unsigned short* __restrict__ A,
    const unsigned short* __restrict__ Bw,
    float* __restrict__ C)
{
  __shared__ short As[128 * 64];
  __shared__ short Bs[128 * 64];
  const int tid = threadIdx.x;
  const int lane = tid & 63, wave = tid >> 6;
  const int wm = wave >> 1, wn = wave & 1;
  const int m0 = blockIdx.y * 128, n0 = blockIdx.x * 128;
  const int r = lane & 15, kg = lane >> 4;

  const f32x4 vzero = {0.f, 0.f, 0.f, 0.f};
  f32x4 acc[4][4];
#pragma unroll
  for (int i = 0; i < 4; ++i)
#pragma unroll
    for (int j = 0; j < 4; ++j) acc[i][j] = vzero;

  for (int kt = 0; kt < 8; ++kt) {
    const int k0 = kt * 64;
#pragma unroll
    for (int j = 0; j < 4; ++j) {
      int e = j * 2048 + tid * 8;
      int row = e >> 6, col = e & 63;
      *(short8*)(As + e) = *(const short8*)(A + (m0 + row) * 512 + k0 + col);
      *(short8*)(Bs + e) = *(const short8*)(Bw + (n0 + row) * 512 + k0 + col);
    }
    __syncthreads();
#pragma unroll
    for (int ks = 0; ks < 2; ++ks) {
      short8 af[4], bfr[4];
#pragma unroll
      for (int mi = 0; mi < 4; ++mi)
        af[mi] = *(const short8*)(As + (wm * 64 + mi * 16 + r) * 64 + ks * 32 + kg * 8);
#pragma unroll
      for (int ni = 0; ni < 4; ++ni)
        bfr[ni] = *(const short8*)(Bs + (wn * 64 + ni * 16 + r) * 64 + ks * 32 + kg * 8);
#pragma unroll
      for (int mi = 0; mi < 4; ++mi)
#pragma unroll
        for (int ni = 0; ni < 4; ++ni)
          acc[mi][ni] = mfma16(af[mi], bfr[ni], acc[mi][ni]);
    }
    __syncthreads();
  }
  const int cc = lane & 15, rr4 = (lane >> 4) * 4;
#pragma unroll
  for (int mi = 0; mi < 4; ++mi) {
#pragma unroll
    for (int ni = 0; ni < 4; ++ni) {
      int gm = m0 + wm * 64 + mi * 16 + rr4;
      int gn = n0 + wn * 64 + ni * 16 + cc;
#pragma unroll
      for (int j = 0; j < 4; ++j) C[(gm + j) * 2048 + gn] = acc[mi][ni][j];
    }
  }
}

// ---------------- Phase 2: persistent recurrence (flagless) ----------------
__global__ __launch_bounds__(512, 2) void lstm_seq(
    const float* __restrict__ gx,            // chunk [T_CHUNK][32][2048]
    const unsigned short* __restrict__ Whb,  // [2048][512] bf16
    const float* __restrict__ bias,          // [2048]
    const float* __restrict__ c0,            // [32][512]
    unsigned short* __restrict__ hseq,       // [1025][32][512] bf16, sentinel-filled
    float* __restrict__ cbuf,                // [32][512]
    float* __restrict__ out,                 // full d_out
    int t0)
{
  const int g = blockIdx.x;
  const int tid = threadIdx.x;
  const int lane = tid & 63, wave = tid >> 6;
  const int mt = wave >> 2, nt = wave & 3;   // batch half, gate
  const int r = lane & 15, kg = lane >> 4;

  // B fragments: Wh rows for gate nt, units g*32 + ct*16 + r, 16 K-slices
  short8 bfrag[2][16];
#pragma unroll
  for (int ct = 0; ct < 2; ++ct) {
    const int urow = nt * HH + g * 32 + ct * 16 + r;
#pragma unroll
    for (int s = 0; s < 16; ++s)
      bfrag[ct][s] = *(const short8*)((const short*)Whb + urow * HH + s * 32 + kg * 8);
  }
#pragma unroll
  for (int ct = 0; ct < 2; ++ct)
#pragma unroll
    for (int s = 0; s < 16; ++s)
      asm volatile("" : "+v"(bfrag[ct][s]));

  // cell mapping: thread -> (batch b, units u2, u2+1)
  const int b = tid >> 4, u2 = (tid & 15) * 2;
  const int unit0 = g * 32 + u2;
  const float bi0 = bias[0 * HH + unit0], bi1 = bias[0 * HH + unit0 + 1];
  const float bf0 = bias[1 * HH + unit0], bf1 = bias[1 * HH + unit0 + 1];
  const float bg0 = bias[2 * HH + unit0], bg1 = bias[2 * HH + unit0 + 1];
  const float bo0 = bias[3 * HH + unit0], bo1 = bias[3 * HH + unit0 + 1];
  float cst0, cst1;
  if (t0 == 0) { cst0 = c0[b * HH + unit0]; cst1 = c0[b * HH + unit0 + 1]; }
  else         { cst0 = cbuf[b * HH + unit0]; cst1 = cbuf[b * HH + unit0 + 1]; }

  __shared__ unsigned short hs[BB * HH];   // XOR-swizzled h tile (32 KB)
  __shared__ float gbuf[4][BB][32];        // gate pre-acts (16 KB)

  const long long hTO = (long long)T_TOT * BB * HH;
  const long long cTO = hTO + BB * HH;
  const long long ahO = cTO + BB * HH;

  // staging indices (constant per thread): wave w covers u64-cols [w*16,w*16+16)
  int u64idx[8];
#pragma unroll
  for (int i = 0; i < 8; ++i) {
    int idx = i * 64 + lane;                // 0..511
    int row = idx >> 4, c4 = idx & 15;
    u64idx[i] = row * 128 + wave * 16 + c4;
  }

  for (int tt = 0; tt < T_CHUNK; ++tt) {
    const int t = t0 + tt;
    // gx prefetch (plain cached loads; line-exact for this block)
    const float* gxp = gx + (long long)tt * BB * G4 + b * G4 + unit0;
    const float2 xi = *(const float2*)(gxp + 0 * HH);
    const float2 xf = *(const float2*)(gxp + 1 * HH);
    const float2 xg = *(const float2*)(gxp + 2 * HH);
    const float2 xo = *(const float2*)(gxp + 3 * HH);

    // poll-load h_t directly: spin until none of my 16 u32 halves is sentinel
    const unsigned long long* hq =
        (const unsigned long long*)(hseq + (size_t)t * (BB * HH));
    unsigned long long q[8];
    {
      unsigned ok, guard = 0;
      do {
        ok = 1u;
#pragma unroll
        for (int i = 0; i < 8; ++i) {
          q[i] = __hip_atomic_load(&hq[u64idx[i]], __ATOMIC_RELAXED,
                                   __HIP_MEMORY_SCOPE_AGENT);
          ok &= ((unsigned)q[i] != SENT32) & ((unsigned)(q[i] >> 32) != SENT32);
        }
      } while (!ok && ++guard < (1u << 16));
    }
    // write to swizzled LDS
#pragma unroll
    for (int i = 0; i < 8; ++i) {
      int idx = i * 64 + lane;
      int row = idx >> 4, c4 = idx & 15;
      int off = (row * 1024 + wave * 128 + c4 * 8) ^ ((row & 7) << 4);
      *(unsigned long long*)((char*)hs + off) = q[i];
    }
    __syncthreads();   // B1: h staged

    // MFMA: gate nt, batches mt*16..+16, 2 col-tiles of 16
    f32x4 aE0 = {0, 0, 0, 0}, aO0 = {0, 0, 0, 0};
    f32x4 aE1 = {0, 0, 0, 0}, aO1 = {0, 0, 0, 0};
    const int abase = (mt * 16 + r) * 1024;
    const int aswz = (r & 7) << 4;
#pragma unroll
    for (int s = 0; s < 16; s += 2) {
      short8 a0 = *(const short8*)((const char*)hs + ((abase + s * 64 + kg * 16) ^ aswz));
      short8 a1 = *(const short8*)((const char*)hs + ((abase + (s + 1) * 64 + kg * 16) ^ aswz));
      aE0 = mfma16(a0, bfrag[0][s], aE0);
      aE1 = mfma16(a0, bfrag[1][s], aE1);
      aO0 = mfma16(a1, bfrag[0][s + 1], aO0);
      aO1 = mfma16(a1, bfrag[1][s + 1], aO1);
    }
    const f32x4 acc0 = aE0 + aO0, acc1 = aE1 + aO1;
#pragma unroll
    for (int j = 0; j < 4; ++j) {
      gbuf[nt][mt * 16 + kg * 4 + j][r] = acc0[j];
      gbuf[nt][mt * 16 + kg * 4 + j][16 + r] = acc1[j];
    }
    __syncthreads();   // B2

    // cell update: 2 cells
    float gi0 = gbuf[0][b][u2] + xi.x + bi0, gi1 = gbuf[0][b][u2 + 1] + xi.y + bi1;
    float gf0_ = gbuf[1][b][u2] + xf.x + bf0, gf1_ = gbuf[1][b][u2 + 1] + xf.y + bf1;
    float gg0 = gbuf[2][b][u2] + xg.x + bg0, gg1 = gbuf[2][b][u2 + 1] + xg.y + bg1;
    float go0 = gbuf[3][b][u2] + xo.x + bo0, go1 = gbuf[3][b][u2 + 1] + xo.y + bo1;
    float si0 = 1.f / (1.f + __expf(-gi0)), si1 = 1.f / (1.f + __expf(-gi1));
    float sf0 = 1.f / (1.f + __expf(-gf0_)), sf1 = 1.f / (1.f + __expf(-gf1_));
    float so0 = 1.f / (1.f + __expf(-go0)), so1 = 1.f / (1.f + __expf(-go1));
    float tg0 = 2.f / (1.f + __expf(-2.f * gg0)) - 1.f;
    float tg1 = 2.f / (1.f + __expf(-2.f * gg1)) - 1.f;
    cst0 = sf0 * cst0 + si0 * tg0;
    cst1 = sf1 * cst1 + si1 * tg1;
    float tc0 = 2.f / (1.f + __expf(-2.f * cst0)) - 1.f;
    float tc1 = 2.f / (1.f + __expf(-2.f * cst1)) - 1.f;
    float hn0 = so0 * tc0, hn1 = so1 * tc1;

    // publish h_{t+1} FIRST (LLC-coherent, packed pair) -- no drain, no flag
    unsigned w32 = (unsigned)f2bf(hn0) | ((unsigned)f2bf(hn1) << 16);
    unsigned* hw = (unsigned*)(hseq + (size_t)(t + 1) * (BB * HH));
    __hip_atomic_store(&hw[(b * HH + unit0) >> 1], w32, __ATOMIC_RELAXED,
                       __HIP_MEMORY_SCOPE_AGENT);

    // outputs (overlap with other blocks' polling)
    long long oidx = (long long)t * BB * HH + b * HH + unit0;
    float2 hv; hv.x = hn0; hv.y = hn1;
    *(float2*)&out[oidx] = hv;
    *(float2*)&out[ahO + oidx] = hv;
    if (t == T_TOT - 1) {
      *(float2*)&out[hTO + b * HH + unit0] = hv;
      float2 cv; cv.x = cst0; cv.y = cst1;
      *(float2*)&out[cTO + b * HH + unit0] = cv;
    }
    if (tt == T_CHUNK - 1) {
      cbuf[b * HH + unit0] = cst0;
      cbuf[b * HH + unit0 + 1] = cst1;
    }
  }
}

extern "C" void kernel_launch(void* const* d_in, const int* in_sizes, int n_in,
                              void* d_out, int out_size, void* d_ws, size_t ws_size,
                              hipStream_t stream) {
  const float* x  = (const float*)d_in[0];
  const float* h0 = (const float*)d_in[1];
  const float* c0 = (const float*)d_in[2];
  const float* Wx = (const float*)d_in[3];
  const float* Wh = (const float*)d_in[4];
  const float* b  = (const float*)d_in[5];
  float* out = (float*)d_out;
  char* ws = (char*)d_ws;

  // ws layout (~100.2 MB)
  float* gx            = (float*)ws;                            // 128*32*2048 f32 = 32 MiB
  unsigned short* xb   = (unsigned short*)(ws + 33554432);      // 32 MiB (full x, bf16)
  unsigned short* Wxb  = (unsigned short*)(ws + 67108864);      // 2 MiB
  unsigned short* Whb  = (unsigned short*)(ws + 69206016);      // 2 MiB
  unsigned short* hseq = (unsigned short*)(ws + 71303168);      // 1025*32KB = 32.03 MiB
  float* cbuf          = (float*)(ws + 104923136);              // 64 KiB

  // sentinel-fill hseq (every call -> deterministic across replays)
  const int n16 = (1025 * BB * HH * 2) / 16;  // 2,099,200 uint4
  fill_sentinel<<<(n16 + 255) / 256, 256, 0, stream>>>((uint4*)hseq, n16);

  // converts: x, Wx, Wh -> bf16; h0 -> hseq slot 0 (after fill)
  cvt_bf16_kernel<<<8192, 256, 0, stream>>>(x, xb, 16777216 / 8);
  cvt_bf16_kernel<<<512, 256, 0, stream>>>(Wx, Wxb, 1048576 / 8);
  cvt_bf16_kernel<<<512, 256, 0, stream>>>(Wh, Whb, 1048576 / 8);
  cvt_bf16_kernel<<<8, 256, 0, stream>>>(h0, hseq, 16384 / 8);

  for (int ch = 0; ch < NCHUNK; ++ch) {
    gemm_gx<<<dim3(16, 32), 256, 0, stream>>>(xb + (size_t)ch * 4096 * 512, Wxb, gx);
    lstm_seq<<<NBLK, 512, 0, stream>>>(gx, Whb, b, c0, hseq, cbuf, out,
                                       ch * T_CHUNK);
  }
}

// Round 5
// 3315.649 us; speedup vs baseline: 3.0238x; 1.0011x over previous
//
#include <hip/hip_runtime.h>
#include <hip/hip_bf16.h>

// LSTM T=1024 B=32 I=H=512.
// Phase 1 (per 128-step chunk): gx = x@Wx^T  (bf16 MFMA, 128x128 tile, fp32 out)
// Phase 2: persistent 16-block x 512-thread recurrence, FLAGLESS sentinel
//          protocol; recurrence kernel is STORE-MINIMAL (1 u32/thread/step);
//          d_out is produced by a post-pass expand kernel from hseq.

typedef __attribute__((ext_vector_type(8))) short short8;
typedef __attribute__((ext_vector_type(4))) float f32x4;

#define T_TOT 1024
#define T_CHUNK 128
#define NCHUNK 8
#define BB 32
#define HH 512
#define G4 2048
#define NBLK 16
#define SENT32 0x7F807F80u

__device__ __forceinline__ unsigned short f2bf(float x) {
  union { float f; unsigned u; } v; v.f = x;
  unsigned r = v.u + 0x7FFFu + ((v.u >> 16) & 1u);
  return (unsigned short)(r >> 16);
}

__device__ __forceinline__ float bf2f(unsigned short h) {
  union { unsigned u; float f; } v; v.u = ((unsigned)h) << 16;
  return v.f;
}

__device__ __forceinline__ f32x4 mfma16(short8 a, short8 b, f32x4 c) {
  return __builtin_amdgcn_mfma_f32_16x16x32_bf16(a, b, c, 0, 0, 0);
}

// ---------------- sentinel fill (uint4 stores) ----------------
__global__ void fill_sentinel(uint4* __restrict__ p, int n16) {
  int i = blockIdx.x * blockDim.x + threadIdx.x;
  if (i >= n16) return;
  uint4 v; v.x = SENT32; v.y = SENT32; v.z = SENT32; v.w = SENT32;
  p[i] = v;
}

// ---------------- f32 -> bf16 convert, 8 elems/thread ----------------
__global__ void cvt_bf16_kernel(const float* __restrict__ src,
                                unsigned short* __restrict__ dst, int n8) {
  int i = blockIdx.x * blockDim.x + threadIdx.x;
  if (i >= n8) return;
  const float4* s4 = (const float4*)src;
  float4 a = s4[2 * i], b = s4[2 * i + 1];
  short8 o;
  o[0] = (short)f2bf(a.x); o[1] = (short)f2bf(a.y);
  o[2] = (short)f2bf(a.z); o[3] = (short)f2bf(a.w);
  o[4] = (short)f2bf(b.x); o[5] = (short)f2bf(b.y);
  o[6] = (short)f2bf(b.z); o[7] = (short)f2bf(b.w);
  *(short8*)(dst + 8 * i) = o;
}

// ---------------- expand: hseq (bf16) -> out 'output' + 'all_hidden' (f32) ----------------
// n8 = T*B*H/8 threads; element e=8i -> t = e/(B*H), src slot t+1.
__global__ __launch_bounds__(256) void expand_out(
    const unsigned short* __restrict__ hseq, float* __restrict__ out,
    long long ahO) {
  long long i = (long long)blockIdx.x * blockDim.x + threadIdx.x;
  long long e = i * 8;
  const short8 v = *(const short8*)(hseq + BB * HH + e);  // slot t+1 == +B*H
  float4 lo, hi;
  lo.x = bf2f((unsigned short)v[0]); lo.y = bf2f((unsigned short)v[1]);
  lo.z = bf2f((unsigned short)v[2]); lo.w = bf2f((unsigned short)v[3]);
  hi.x = bf2f((unsigned short)v[4]); hi.y = bf2f((unsigned short)v[5]);
  hi.z = bf2f((unsigned short)v[6]); hi.w = bf2f((unsigned short)v[7]);
  *(float4*)(out + e) = lo;
  *(float4*)(out + e + 4) = hi;
  *(float4*)(out + ahO + e) = lo;
  *(float4*)(out + ahO + e + 4) = hi;
}

// hT (from hseq slot 1024) + cT (from cbuf f32)
__global__ void final_state(const unsigned short* __restrict__ hseq,
                            const float* __restrict__ cbuf,
                            float* __restrict__ out, long long hTO,
                            long long cTO) {
  int i = blockIdx.x * blockDim.x + threadIdx.x;
  if (i >= BB * HH) return;
  out[hTO + i] = bf2f(hseq[(size_t)T_TOT * BB * HH + i]);
  out[cTO + i] = cbuf[i];
}

// ---------------- Phase 1: C[4096][2048] = A[4096][512] @ Bw[2048][512]^T ----------------
__global__ __launch_bounds__(256) void gemm_gx(
    const unsigned short* __restrict__ A,
    const unsigned short* __restrict__ Bw,
    float* __restrict__ C)
{
  __shared__ short As[128 * 64];
  __shared__ short Bs[128 * 64];
  const int tid = threadIdx.x;
  const int lane = tid & 63, wave = tid >> 6;
  const int wm = wave >> 1, wn = wave & 1;
  const int m0 = blockIdx.y * 128, n0 = blockIdx.x * 128;
  const int r = lane & 15, kg = lane >> 4;

  const f32x4 vzero = {0.f, 0.f, 0.f, 0.f};
  f32x4 acc[4][4];
#pragma unroll
  for (int i = 0; i < 4; ++i)
#pragma unroll
    for (int j = 0; j < 4; ++j) acc[i][j] = vzero;

  for (int kt = 0; kt < 8; ++kt) {
    const int k0 = kt * 64;
#pragma unroll
    for (int j = 0; j < 4; ++j) {
      int e = j * 2048 + tid * 8;
      int row = e >> 6, col = e & 63;
      *(short8*)(As + e) = *(const short8*)(A + (m0 + row) * 512 + k0 + col);
      *(short8*)(Bs + e) = *(const short8*)(Bw + (n0 + row) * 512 + k0 + col);
    }
    __syncthreads();
#pragma unroll
    for (int ks = 0; ks < 2; ++ks) {
      short8 af[4], bfr[4];
#pragma unroll
      for (int mi = 0; mi < 4; ++mi)
        af[mi] = *(const short8*)(As + (wm * 64 + mi * 16 + r) * 64 + ks * 32 + kg * 8);
#pragma unroll
      for (int ni = 0; ni < 4; ++ni)
        bfr[ni] = *(const short8*)(Bs + (wn * 64 + ni * 16 + r) * 64 + ks * 32 + kg * 8);
#pragma unroll
      for (int mi = 0; mi < 4; ++mi)
#pragma unroll
        for (int ni = 0; ni < 4; ++ni)
          acc[mi][ni] = mfma16(af[mi], bfr[ni], acc[mi][ni]);
    }
    __syncthreads();
  }
  const int cc = lane & 15, rr4 = (lane >> 4) * 4;
#pragma unroll
  for (int mi = 0; mi < 4; ++mi) {
#pragma unroll
    for (int ni = 0; ni < 4; ++ni) {
      int gm = m0 + wm * 64 + mi * 16 + rr4;
      int gn = n0 + wn * 64 + ni * 16 + cc;
#pragma unroll
      for (int j = 0; j < 4; ++j) C[(gm + j) * 2048 + gn] = acc[mi][ni][j];
    }
  }
}

// ---------------- Phase 2: persistent recurrence (flagless, store-minimal) ----------------
__global__ __launch_bounds__(512, 2) void lstm_seq(
    const float* __restrict__ gx,            // chunk [T_CHUNK][32][2048]
    const unsigned short* __restrict__ Whb,  // [2048][512] bf16
    const float* __restrict__ bias,          // [2048]
    const float* __restrict__ c0,            // [32][512]
    unsigned short* __restrict__ hseq,       // [1025][32][512] bf16, sentinel-filled
    float* __restrict__ cbuf,                // [32][512]
    int t0)
{
  const int g = blockIdx.x;
  const int tid = threadIdx.x;
  const int lane = tid & 63, wave = tid >> 6;
  const int mt = wave >> 2, nt = wave & 3;   // batch half, gate
  const int r = lane & 15, kg = lane >> 4;

  // B fragments: Wh rows for gate nt, units g*32 + ct*16 + r, 16 K-slices
  short8 bfrag[2][16];
#pragma unroll
  for (int ct = 0; ct < 2; ++ct) {
    const int urow = nt * HH + g * 32 + ct * 16 + r;
#pragma unroll
    for (int s = 0; s < 16; ++s)
      bfrag[ct][s] = *(const short8*)((const short*)Whb + urow * HH + s * 32 + kg * 8);
  }
#pragma unroll
  for (int ct = 0; ct < 2; ++ct)
#pragma unroll
    for (int s = 0; s < 16; ++s)
      asm volatile("" : "+v"(bfrag[ct][s]));

  // cell mapping: thread -> (batch b, units u2, u2+1)
  const int b = tid >> 4, u2 = (tid & 15) * 2;
  const int unit0 = g * 32 + u2;
  const float bi0 = bias[0 * HH + unit0], bi1 = bias[0 * HH + unit0 + 1];
  const float bf0 = bias[1 * HH + unit0], bf1 = bias[1 * HH + unit0 + 1];
  const float bg0 = bias[2 * HH + unit0], bg1 = bias[2 * HH + unit0 + 1];
  const float bo0 = bias[3 * HH + unit0], bo1 = bias[3 * HH + unit0 + 1];
  float cst0, cst1;
  if (t0 == 0) { cst0 = c0[b * HH + unit0]; cst1 = c0[b * HH + unit0 + 1]; }
  else         { cst0 = cbuf[b * HH + unit0]; cst1 = cbuf[b * HH + unit0 + 1]; }

  __shared__ unsigned short hs[BB * HH];   // XOR-swizzled h tile (32 KB)
  __shared__ float gbuf[4][BB][32];        // gate pre-acts (16 KB)

  // staging indices (constant per thread): wave w covers u64-cols [w*16,w*16+16)
  int u64idx[8];
#pragma unroll
  for (int i = 0; i < 8; ++i) {
    int idx = i * 64 + lane;                // 0..511
    int row = idx >> 4, c4 = idx & 15;
    u64idx[i] = row * 128 + wave * 16 + c4;
  }

  for (int tt = 0; tt < T_CHUNK; ++tt) {
    const int t = t0 + tt;
    // gx prefetch (plain cached loads; line-exact for this block)
    const float* gxp = gx + (long long)tt * BB * G4 + b * G4 + unit0;
    const float2 xi = *(const float2*)(gxp + 0 * HH);
    const float2 xf = *(const float2*)(gxp + 1 * HH);
    const float2 xg = *(const float2*)(gxp + 2 * HH);
    const float2 xo = *(const float2*)(gxp + 3 * HH);

    // poll-load h_t directly: spin until none of my 16 u32 halves is sentinel
    const unsigned long long* hq =
        (const unsigned long long*)(hseq + (size_t)t * (BB * HH));
    unsigned long long q[8];
    {
      unsigned ok, guard = 0;
      do {
        ok = 1u;
#pragma unroll
        for (int i = 0; i < 8; ++i) {
          q[i] = __hip_atomic_load(&hq[u64idx[i]], __ATOMIC_RELAXED,
                                   __HIP_MEMORY_SCOPE_AGENT);
          ok &= ((unsigned)q[i] != SENT32) & ((unsigned)(q[i] >> 32) != SENT32);
        }
      } while (!ok && ++guard < (1u << 16));
    }
    // write to swizzled LDS
#pragma unroll
    for (int i = 0; i < 8; ++i) {
      int idx = i * 64 + lane;
      int row = idx >> 4, c4 = idx & 15;
      int off = (row * 1024 + wave * 128 + c4 * 8) ^ ((row & 7) << 4);
      *(unsigned long long*)((char*)hs + off) = q[i];
    }
    __syncthreads();   // B1: h staged

    // MFMA: gate nt, batches mt*16..+16, 2 col-tiles of 16
    f32x4 aE0 = {0, 0, 0, 0}, aO0 = {0, 0, 0, 0};
    f32x4 aE1 = {0, 0, 0, 0}, aO1 = {0, 0, 0, 0};
    const int abase = (mt * 16 + r) * 1024;
    const int aswz = (r & 7) << 4;
#pragma unroll
    for (int s = 0; s < 16; s += 2) {
      short8 a0 = *(const short8*)((const char*)hs + ((abase + s * 64 + kg * 16) ^ aswz));
      short8 a1 = *(const short8*)((const char*)hs + ((abase + (s + 1) * 64 + kg * 16) ^ aswz));
      aE0 = mfma16(a0, bfrag[0][s], aE0);
      aE1 = mfma16(a0, bfrag[1][s], aE1);
      aO0 = mfma16(a1, bfrag[0][s + 1], aO0);
      aO1 = mfma16(a1, bfrag[1][s + 1], aO1);
    }
    const f32x4 acc0 = aE0 + aO0, acc1 = aE1 + aO1;
#pragma unroll
    for (int j = 0; j < 4; ++j) {
      gbuf[nt][mt * 16 + kg * 4 + j][r] = acc0[j];
      gbuf[nt][mt * 16 + kg * 4 + j][16 + r] = acc1[j];
    }
    __syncthreads();   // B2

    // cell update: 2 cells
    float gi0 = gbuf[0][b][u2] + xi.x + bi0, gi1 = gbuf[0][b][u2 + 1] + xi.y + bi1;
    float gf0_ = gbuf[1][b][u2] + xf.x + bf0, gf1_ = gbuf[1][b][u2 + 1] + xf.y + bf1;
    float gg0 = gbuf[2][b][u2] + xg.x + bg0, gg1 = gbuf[2][b][u2 + 1] + xg.y + bg1;
    float go0 = gbuf[3][b][u2] + xo.x + bo0, go1 = gbuf[3][b][u2 + 1] + xo.y + bo1;
    float si0 = 1.f / (1.f + __expf(-gi0)), si1 = 1.f / (1.f + __expf(-gi1));
    float sf0 = 1.f / (1.f + __expf(-gf0_)), sf1 = 1.f / (1.f + __expf(-gf1_));
    float so0 = 1.f / (1.f + __expf(-go0)), so1 = 1.f / (1.f + __expf(-go1));
    float tg0 = 2.f / (1.f + __expf(-2.f * gg0)) - 1.f;
    float tg1 = 2.f / (1.f + __expf(-2.f * gg1)) - 1.f;
    cst0 = sf0 * cst0 + si0 * tg0;
    cst1 = sf1 * cst1 + si1 * tg1;
    float tc0 = 2.f / (1.f + __expf(-2.f * cst0)) - 1.f;
    float tc1 = 2.f / (1.f + __expf(-2.f * cst1)) - 1.f;
    float hn0 = so0 * tc0, hn1 = so1 * tc1;

    // publish h_{t+1} (LLC-coherent, packed pair) -- the ONLY per-step store
    unsigned w32 = (unsigned)f2bf(hn0) | ((unsigned)f2bf(hn1) << 16);
    unsigned* hw = (unsigned*)(hseq + (size_t)(t + 1) * (BB * HH));
    __hip_atomic_store(&hw[(b * HH + unit0) >> 1], w32, __ATOMIC_RELAXED,
                       __HIP_MEMORY_SCOPE_AGENT);

    if (tt == T_CHUNK - 1) {
      cbuf[b * HH + unit0] = cst0;
      cbuf[b * HH + unit0 + 1] = cst1;
    }
  }
}

extern "C" void kernel_launch(void* const* d_in, const int* in_sizes, int n_in,
                              void* d_out, int out_size, void* d_ws, size_t ws_size,
                              hipStream_t stream) {
  const float* x  = (const float*)d_in[0];
  const float* h0 = (const float*)d_in[1];
  const float* c0 = (const float*)d_in[2];
  const float* Wx = (const float*)d_in[3];
  const float* Wh = (const float*)d_in[4];
  const float* b  = (const float*)d_in[5];
  float* out = (float*)d_out;
  char* ws = (char*)d_ws;

  // ws layout (~100.2 MB)
  float* gx            = (float*)ws;                            // 32 MiB
  unsigned short* xb   = (unsigned short*)(ws + 33554432);      // 32 MiB (full x, bf16)
  unsigned short* Wxb  = (unsigned short*)(ws + 67108864);      // 2 MiB
  unsigned short* Whb  = (unsigned short*)(ws + 69206016);      // 2 MiB
  unsigned short* hseq = (unsigned short*)(ws + 71303168);      // 1025*32KB = 32.03 MiB
  float* cbuf          = (float*)(ws + 104923136);              // 64 KiB

  const long long hTO = (long long)T_TOT * BB * HH;
  const long long cTO = hTO + BB * HH;
  const long long ahO = cTO + BB * HH;

  // sentinel-fill hseq (every call -> deterministic across replays)
  const int n16 = (1025 * BB * HH * 2) / 16;
  fill_sentinel<<<(n16 + 255) / 256, 256, 0, stream>>>((uint4*)hseq, n16);

  // converts: x, Wx, Wh -> bf16; h0 -> hseq slot 0 (after fill)
  cvt_bf16_kernel<<<8192, 256, 0, stream>>>(x, xb, 16777216 / 8);
  cvt_bf16_kernel<<<512, 256, 0, stream>>>(Wx, Wxb, 1048576 / 8);
  cvt_bf16_kernel<<<512, 256, 0, stream>>>(Wh, Whb, 1048576 / 8);
  cvt_bf16_kernel<<<8, 256, 0, stream>>>(h0, hseq, 16384 / 8);

  for (int ch = 0; ch < NCHUNK; ++ch) {
    gemm_gx<<<dim3(16, 32), 256, 0, stream>>>(xb + (size_t)ch * 4096 * 512, Wxb, gx);
    lstm_seq<<<NBLK, 512, 0, stream>>>(gx, Whb, b, c0, hseq, cbuf, ch * T_CHUNK);
  }

  // post-pass: materialize d_out from hseq (+ final c)
  expand_out<<<8192, 256, 0, stream>>>(hseq, out, ahO);
  final_state<<<64, 256, 0, stream>>>(hseq, cbuf, out, hTO, cTO);
}